// Round 6
// baseline (220.718 us; speedup 1.0000x reference)
//
#include <hip/hip_runtime.h>
#include <stdint.h>

#define V_DIM 32000
#define M_TOT 4096      // B*S
#define NF 128          // 2*n_freq
#define NC 256          // channels
#define BM 64           // M-tile
#define BK 64           // K-step (256B per x-row per step -> DRAM-friendly)
#define K64 500         // V_DIM / BK
#define NSPL 12         // 64 mt * 12 ks = 768 blocks = exactly 3/CU
#define ASTRE 72        // A LDS row stride in bf16 elems (144B -> +1 bank-quad/row)
#define BSTR 130        // B LDS slot stride per kg-plane (16B slots)
#define THREADS 256

typedef __bf16 bf16x8 __attribute__((ext_vector_type(8)));
typedef float f32x4 __attribute__((ext_vector_type(4)));

__device__ __forceinline__ unsigned short f2bf(float f) {  // RNE (table build)
  unsigned int u = __float_as_uint(f);
  u += 0x7FFFu + ((u >> 16) & 1u);
  return (unsigned short)(u >> 16);
}

// two fp32 -> packed bf16x2 by truncation (1 v_perm); absmax impact measured safe (R4)
__device__ __forceinline__ unsigned int pk2(float lo, float hi) {
  return __builtin_amdgcn_perm(__float_as_uint(hi), __float_as_uint(lo), 0x07060302u);
}

// ---------------- Stage 0: DFT basis table in THREAD-STAGING order (BK=64) ----------
// chunk c (64 k-values): 1024 slots of 8 bf16. slot gid = q*256 + t (q=0..3).
//   kgc = gid>>7 (0..7), row = gid&127; element e -> T_log[row][c*64 + kgc*8 + e]
//   T_log[f][v] = cos(2pi(f+1)v/V) f<64 ; -sin(2pi(f-63)v/V) f>=64
// gemm1 thread t: 4 contiguous int4 loads at gid = t, 256+t, 512+t, 768+t.
__global__ __launch_bounds__(256) void build_table(unsigned short* __restrict__ T) {
  int id = blockIdx.x * 256 + threadIdx.x;
  if (id >= 1024 * K64) return;                   // 512000
  int c = id >> 10;
  int r = id & 1023;
  int kgc = r >> 7;
  int row = r & 127;
  int k = (row < 64) ? (row + 1) : (row - 63);
  bool is_cos = (row < 64);
  int vb = c * 64 + kgc * 8;
  const float w0 = 6.283185307179586f / (float)V_DIM;
  union { unsigned short us[8]; int4 v; } u;
  #pragma unroll
  for (int e = 0; e < 8; ++e) {
    int m = (k * (vb + e)) % V_DIM;               // exact range reduction
    float s, cc;
    __sincosf((float)m * w0, &s, &cc);
    u.us[e] = f2bf(is_cos ? cc : -s);
  }
  *reinterpret_cast<int4*>(T + (size_t)id * 8) = u.v;
}

// ---------------- Stage 1: P[ks] = x_tile @ T_chunk^T (BK=64) ----------------
__global__ __launch_bounds__(THREADS) void gemm1(
    const float* __restrict__ x, const unsigned short* __restrict__ T,
    float* __restrict__ P) {
  __shared__ __align__(16) unsigned short As[2][BM * ASTRE];   // 9216 B / buf
  __shared__ __align__(16) unsigned short Bs[2][8 * BSTR * 8]; // 16640 B / buf

  const int b = blockIdx.x;
  const int ks = b % NSPL;            // same-ks blocks land on 2 XCDs -> T slice L2-hot
  const int mt = b / NSPL;            // 0..63
  const int m0 = mt * BM;

  const int basek = K64 / NSPL, remk = K64 % NSPL;   // 41, 8
  const int steps = basek + (ks < remk);
  const int start = ks * basek + (ks < remk ? ks : remk);

  const int t = threadIdx.x;
  const int lane = t & 63, wave = t >> 6;
  const int wm = wave >> 1, wn = wave & 1;   // wave tile 32m x 64n
  const int kgl = lane >> 4, rl = lane & 15;

  // A staging: thread -> (row, 64B k-segment)
  const int row_a = t >> 2, kseg = t & 3;
  const float* xa = x + (size_t)(m0 + row_a) * V_DIM + (size_t)start * BK + kseg * 16;
  const int awr = row_a * ASTRE + kseg * 16;  // short offset of this thread's 32B

  // B staging: 4 int4 at gid = q*256+t; write slot kgc*BSTR+row
  const unsigned short* Tc = T + (size_t)start * 8192;

  f32x4 acc[2][4];
  #pragma unroll
  for (int a = 0; a < 2; ++a)
    #pragma unroll
    for (int c = 0; c < 4; ++c) acc[a][c] = (f32x4){0.f, 0.f, 0.f, 0.f};

  int bslot[4];
  #pragma unroll
  for (int q = 0; q < 4; ++q) {
    int gid = q * 256 + t;
    bslot[q] = (gid >> 7) * BSTR + (gid & 127);
  }

  auto consume = [&](int buf, float4* xv, int4* bv) {
    #pragma unroll
    for (int q = 0; q < 4; ++q)
      *reinterpret_cast<int4*>(&Bs[buf][bslot[q] * 8]) = bv[q];
    uint4 w0, w1;
    w0.x = pk2(xv[0].x, xv[0].y); w0.y = pk2(xv[0].z, xv[0].w);
    w0.z = pk2(xv[1].x, xv[1].y); w0.w = pk2(xv[1].z, xv[1].w);
    w1.x = pk2(xv[2].x, xv[2].y); w1.y = pk2(xv[2].z, xv[2].w);
    w1.z = pk2(xv[3].x, xv[3].y); w1.w = pk2(xv[3].z, xv[3].w);
    *reinterpret_cast<uint4*>(&As[buf][awr]) = w0;
    *reinterpret_cast<uint4*>(&As[buf][awr + 8]) = w1;
  };

  // ---- prologue: stage step 0 into buf0
  {
    int4 bv[4];
    float4 xv[4];
    #pragma unroll
    for (int q = 0; q < 4; ++q)
      bv[q] = *reinterpret_cast<const int4*>(Tc + (size_t)(q * 256 + t) * 8);
    #pragma unroll
    for (int i = 0; i < 4; ++i)
      xv[i] = *reinterpret_cast<const float4*>(xa + i * 4);
    consume(0, xv, bv);
    __syncthreads();
  }

  for (int s = 0; s < steps; ++s) {
    const int cur = s & 1, nxt = cur ^ 1;
    const bool pre = (s + 1 < steps);

    // 1) issue next step's 8 global loads first (T first, then x)
    int4 bv[4];
    float4 xv[4];
    if (pre) {
      const unsigned short* tp = Tc + (size_t)(s + 1) * 8192;
      #pragma unroll
      for (int q = 0; q < 4; ++q)
        bv[q] = *reinterpret_cast<const int4*>(tp + (size_t)(q * 256 + t) * 8);
      const float* xp = xa + (size_t)(s + 1) * BK;
      #pragma unroll
      for (int i = 0; i < 4; ++i)
        xv[i] = *reinterpret_cast<const float4*>(xp + i * 4);
    }

    // 2) MFMAs on current buffer (cover part of the load latency)
    #pragma unroll
    for (int kk = 0; kk < 2; ++kk) {
      bf16x8 bfr[4];
      #pragma unroll
      for (int nf = 0; nf < 4; ++nf)
        bfr[nf] = *reinterpret_cast<const bf16x8*>(
            &Bs[cur][((kk * 4 + kgl) * BSTR + wn * 64 + nf * 16 + rl) * 8]);
      #pragma unroll
      for (int mf = 0; mf < 2; ++mf) {
        bf16x8 av = *reinterpret_cast<const bf16x8*>(
            &As[cur][(wm * 32 + mf * 16 + rl) * ASTRE + kk * 32 + kgl * 8]);
        #pragma unroll
        for (int nf = 0; nf < 4; ++nf)
          acc[mf][nf] = __builtin_amdgcn_mfma_f32_16x16x32_bf16(
              av, bfr[nf], acc[mf][nf], 0, 0, 0);
      }
    }

    // 3) consume loads mid-step; barrier drain stays nearly empty
    if (pre) consume(nxt, xv, bv);
    __syncthreads();
  }

  // ---- epilogue: partial [64 x 128] tile for this k-split
  float* Pp = P + ((size_t)ks * M_TOT + m0) * NF;
  const int r0 = (lane >> 4) * 4;
  const int col = lane & 15;
  #pragma unroll
  for (int mf = 0; mf < 2; ++mf)
    #pragma unroll
    for (int nf = 0; nf < 4; ++nf)
      #pragma unroll
      for (int q = 0; q < 4; ++q) {
        int row = wm * 32 + mf * 16 + r0 + q;
        int n = wn * 64 + nf * 16 + col;
        Pp[(size_t)row * NF + n] = acc[mf][nf][q];
      }
}

// ---------------- Stage 2: out = (sum_s P[s]) @ W^T ----------------
__global__ __launch_bounds__(256) void gemm2(
    const float* __restrict__ P, const float* __restrict__ W,
    float* __restrict__ out, int NS) {
  __shared__ __align__(16) float Xr[8][NF];
  const int mb = blockIdx.x * 8;
  const int t = threadIdx.x;

  #pragma unroll
  for (int i = 0; i < 4; ++i) {
    int idx = t + i * 256;           // 8 rows x 128 freqs
    int r = idx >> 7, f = idx & 127;
    float s = 0.f;
    for (int sp = 0; sp < NS; ++sp)
      s += P[((size_t)sp * M_TOT + mb + r) * NF + f];
    Xr[r][f] = s;
  }
  __syncthreads();

  const float4* Wr = reinterpret_cast<const float4*>(W + (size_t)t * NF);
  float accr[8];
  #pragma unroll
  for (int r = 0; r < 8; ++r) accr[r] = 0.f;

  for (int f4 = 0; f4 < NF / 4; ++f4) {
    float4 w = Wr[f4];
    #pragma unroll
    for (int r = 0; r < 8; ++r) {
      float4 xv = *reinterpret_cast<const float4*>(&Xr[r][f4 * 4]);
      accr[r] += xv.x * w.x + xv.y * w.y + xv.z * w.z + xv.w * w.w;
    }
  }
  #pragma unroll
  for (int r = 0; r < 8; ++r)
    out[(size_t)(mb + r) * NC + t] = accr[r];
}

extern "C" void kernel_launch(void* const* d_in, const int* in_sizes, int n_in,
                              void* d_out, int out_size, void* d_ws, size_t ws_size,
                              hipStream_t stream) {
  const float* x = (const float*)d_in[0];
  const float* w = (const float*)d_in[1];
  float* out = (float*)d_out;

  unsigned short* T = (unsigned short*)d_ws;
  const size_t t_bytes = (size_t)NF * V_DIM * sizeof(unsigned short); // 8,192,000
  float* P = (float*)((char*)d_ws + t_bytes);
  // ws need: 8 MB (T) + 12 * 2 MiB (P) = ~33 MB (R4 ran fine with 40 MB).

  build_table<<<dim3(2000), dim3(256), 0, stream>>>(T);
  gemm1<<<dim3(64 * NSPL), dim3(THREADS), 0, stream>>>(x, T, P);
  gemm2<<<dim3(M_TOT / 8), dim3(256), 0, stream>>>(P, w, out, NSPL);
}

// Round 7
// 159.862 us; speedup vs baseline: 1.3807x; 1.3807x over previous
//
#include <hip/hip_runtime.h>
#include <stdint.h>

#define V_DIM 32000
#define M_TOT 4096      // B*S
#define NF 128          // 2*n_freq
#define NC 256          // channels
#define BM 128          // M-tile
#define BK 32           // K-step
#define THREADS 256

typedef __bf16 bf16x8 __attribute__((ext_vector_type(8)));
typedef float f32x4 __attribute__((ext_vector_type(4)));

__device__ __forceinline__ unsigned short f2bf(float f) {  // RNE (table build)
  unsigned int u = __float_as_uint(f);
  u += 0x7FFFu + ((u >> 16) & 1u);
  return (unsigned short)(u >> 16);
}

// two fp32 -> packed bf16x2 by truncation (1 v_perm); measured safe (R4/R6 absmax 1.0 << 2.96)
__device__ __forceinline__ unsigned int pk2(float lo, float hi) {
  return __builtin_amdgcn_perm(__float_as_uint(hi), __float_as_uint(lo), 0x07060302u);
}

__device__ __forceinline__ void gllA(const float* g, const float* l) {
  __builtin_amdgcn_global_load_lds(
      (const __attribute__((address_space(1))) void*)g,
      (__attribute__((address_space(3))) void*)l, 16, 0, 0);
}
__device__ __forceinline__ void gllB(const unsigned short* g, const unsigned short* l) {
  __builtin_amdgcn_global_load_lds(
      (const __attribute__((address_space(1))) void*)g,
      (__attribute__((address_space(3))) void*)l, 16, 0, 0);
}

// ---------------- Stage 0: DFT table in LDS-LINEAR-STAGING order with baked swizzle ----
// gemm1 stages 512 chunks (16B) per step fully linearly: chunk id -> LDS offset id*16.
// id = q*256 + wave*64 + lane ; LDS (col, slot): col = q*64 + wave*16 + (lane>>2),
// slot = lane&3. We bake kg = slot ^ m(col), m(col) = (col + (col>>2)) & 3 so that
// fragment reads (kg fixed per lane) spread banks. Chunk content: elem e ->
//   T_log[col][cstep*32 + kg*8 + e];  T_log[f][v] = cos(2pi(f+1)v/V) (f<64),
//                                     -sin(2pi(f-63)v/V) (f>=64)
__global__ __launch_bounds__(256) void build_table(unsigned short* __restrict__ T) {
  int id = blockIdx.x * 256 + threadIdx.x;
  if (id >= 512 * 1000) return;
  int cstep = id >> 9;
  int r = id & 511;
  int q = r >> 8;
  int tt = r & 255;
  int w = tt >> 6, l = tt & 63;
  int col = q * 64 + w * 16 + (l >> 2);
  int m = (col + (col >> 2)) & 3;
  int kg = (l & 3) ^ m;
  int k = (col < 64) ? (col + 1) : (col - 63);
  bool is_cos = (col < 64);
  int vb = cstep * 32 + kg * 8;
  const float w0 = 6.283185307179586f / (float)V_DIM;
  union { unsigned short us[8]; int4 v; } u;
  #pragma unroll
  for (int e = 0; e < 8; ++e) {
    int mm = (k * (vb + e)) % V_DIM;              // exact range reduction
    float s, cc;
    __sincosf((float)mm * w0, &s, &cc);
    u.us[e] = f2bf(is_cos ? cc : -s);
  }
  *reinterpret_cast<int4*>(T + (size_t)id * 8) = u.v;
}

// ---------------- Stage 1: P[ks] = x_tile @ T_chunk^T  (m97-style gll staging) --------
__global__ __launch_bounds__(THREADS) void gemm1(
    const float* __restrict__ x, const unsigned short* __restrict__ T,
    float* __restrict__ P, int NS, int G) {
  __shared__ __align__(16) float As[2][4096];           // fp32 A tile, 16 KB/buf
  __shared__ __align__(16) unsigned short Bs[2][4096];  // bf16 B tile,  8 KB/buf

  // XCD pinning: xcd j = b&7 sees only ks ≡ j (mod 8) -> its T slice stays L2-hot
  const int b = blockIdx.x;
  const int j = b & 7;
  const int rest = b >> 3;
  const int ks = j + 8 * (rest % G);
  const int mt = rest / G;              // 0..31
  const int m0 = mt * BM;

  const int basek = 1000 / NS, remk = 1000 % NS;
  const int steps = basek + (ks < remk);
  const int start = ks * basek + (ks < remk ? ks : remk);

  const int t = threadIdx.x;
  const int lane = t & 63, wave = t >> 6;
  const int wm = wave >> 1, wn = wave & 1;   // 2x2 waves, wave tile 64m x 64n
  const int kgl = lane >> 4, rl = lane & 15;

  // A staging geometry: instr i covers rows i*32 + wave*8 + (lane>>3), 8 chunks/row.
  // Source chunk csub = (lane&7) ^ rsub  => LDS slot (lane&7) = chunk ^ (row&7):
  // XOR bank swizzle realized purely on the per-lane GLOBAL address (m173).
  const int rsub = lane >> 3;
  const int csub = (lane & 7) ^ rsub;
  const float* xbase = x + (size_t)(m0 + wave * 8 + rsub) * V_DIM + csub * 4
                         + (size_t)start * BK;
  const unsigned short* Tb = T + (size_t)start * 4096;  // 512 chunks * 8 ush per step

  f32x4 acc[4][4];
  #pragma unroll
  for (int a = 0; a < 4; ++a)
    #pragma unroll
    for (int c = 0; c < 4; ++c) acc[a][c] = (f32x4){0.f, 0.f, 0.f, 0.f};

  auto stage = [&](int s, int buf) {
    const float* xs = xbase + (size_t)s * BK;
    #pragma unroll
    for (int i = 0; i < 4; ++i)
      gllA(xs + (size_t)i * 32 * V_DIM, &As[buf][i * 1024 + wave * 256]);
    const unsigned short* ts = Tb + (size_t)s * 4096 + t * 8;
    #pragma unroll
    for (int q = 0; q < 2; ++q)
      gllB(ts + q * 2048, &Bs[buf][q * 2048 + wave * 512]);
  };

  // lane-constant pieces of the B read address
  const int mB = (rl + (rl >> 2)) & 3;        // == m(col) for col = wn*64+nf*16+rl
  const int bslot = (kgl ^ mB) * 8;           // ushort offset within col

  stage(0, 0);
  __syncthreads();

  for (int s = 0; s < steps; ++s) {
    const int cur = s & 1, nxt = cur ^ 1;
    if (s + 1 < steps) stage(s + 1, nxt);     // 6 gll issued first, in flight over compute

    // B fragments
    bf16x8 bfr[4];
    #pragma unroll
    for (int nf = 0; nf < 4; ++nf) {
      int col = wn * 64 + nf * 16 + rl;
      bfr[nf] = *reinterpret_cast<const bf16x8*>(&Bs[cur][col * 32 + bslot]);
    }
    // A fragments (fp32 -> bf16 in reg) + MFMA
    #pragma unroll
    for (int mf = 0; mf < 4; ++mf) {
      int row = wm * 64 + mf * 16 + rl;
      int base = row * 32;                    // floats
      float4 lo = *reinterpret_cast<const float4*>(
          &As[cur][base + (((2 * kgl) ^ (row & 7)) * 4)]);
      float4 hi = *reinterpret_cast<const float4*>(
          &As[cur][base + (((2 * kgl + 1) ^ (row & 7)) * 4)]);
      union { uint4 u; bf16x8 v; } a8;
      a8.u.x = pk2(lo.x, lo.y); a8.u.y = pk2(lo.z, lo.w);
      a8.u.z = pk2(hi.x, hi.y); a8.u.w = pk2(hi.z, hi.w);
      #pragma unroll
      for (int nf = 0; nf < 4; ++nf)
        acc[mf][nf] = __builtin_amdgcn_mfma_f32_16x16x32_bf16(
            a8.v, bfr[nf], acc[mf][nf], 0, 0, 0);
    }
    __syncthreads();   // drains vmcnt(0): buf nxt complete, buf cur reads done
  }

  // ---- epilogue: partial [128 x 128] tile for this k-split
  float* Pp = P + ((size_t)ks * M_TOT + m0) * NF;
  const int r0 = (lane >> 4) * 4;
  const int col = lane & 15;
  #pragma unroll
  for (int mf = 0; mf < 4; ++mf)
    #pragma unroll
    for (int nf = 0; nf < 4; ++nf)
      #pragma unroll
      for (int q = 0; q < 4; ++q) {
        int row = wm * 64 + mf * 16 + r0 + q;
        int n = wn * 64 + nf * 16 + col;
        Pp[(size_t)row * NF + n] = acc[mf][nf][q];
      }
}

// ---------------- Stage 2: out = (sum_s P[s]) @ W^T ----------------
__global__ __launch_bounds__(256) void gemm2(
    const float* __restrict__ P, const float* __restrict__ W,
    float* __restrict__ out, int NS) {
  __shared__ __align__(16) float Xr[8][NF];
  const int mb = blockIdx.x * 8;
  const int t = threadIdx.x;

  #pragma unroll
  for (int i = 0; i < 4; ++i) {
    int idx = t + i * 256;           // 8 rows x 128 freqs
    int r = idx >> 7, f = idx & 127;
    float s = 0.f;
    for (int sp = 0; sp < NS; ++sp)
      s += P[((size_t)sp * M_TOT + mb + r) * NF + f];
    Xr[r][f] = s;
  }
  __syncthreads();

  const float4* Wr = reinterpret_cast<const float4*>(W + (size_t)t * NF);
  float accr[8];
  #pragma unroll
  for (int r = 0; r < 8; ++r) accr[r] = 0.f;

  for (int f4 = 0; f4 < NF / 4; ++f4) {
    float4 w = Wr[f4];
    #pragma unroll
    for (int r = 0; r < 8; ++r) {
      float4 xv = *reinterpret_cast<const float4*>(&Xr[r][f4 * 4]);
      accr[r] += xv.x * w.x + xv.y * w.y + xv.z * w.z + xv.w * w.w;
    }
  }
  #pragma unroll
  for (int r = 0; r < 8; ++r)
    out[(size_t)(mb + r) * NC + t] = accr[r];
}

extern "C" void kernel_launch(void* const* d_in, const int* in_sizes, int n_in,
                              void* d_out, int out_size, void* d_ws, size_t ws_size,
                              hipStream_t stream) {
  const float* x = (const float*)d_in[0];
  const float* w = (const float*)d_in[1];
  float* out = (float*)d_out;

  unsigned short* T = (unsigned short*)d_ws;
  const size_t t_bytes = (size_t)NF * V_DIM * sizeof(unsigned short); // 8,192,000
  float* P = (float*)((char*)d_ws + t_bytes);
  const size_t p_split_bytes = (size_t)M_TOT * NF * sizeof(float);    // 2 MiB

  // NS=24 -> 768 blocks = 3/CU (LDS 48KB allows 3). Fall back by 8s if ws is small.
  int NS = 24;
  while (NS > 8 && ws_size < t_bytes + (size_t)NS * p_split_bytes) NS -= 8;
  const int G = NS / 8;

  build_table<<<dim3(2000), dim3(256), 0, stream>>>(T);
  gemm1<<<dim3(32 * NS), dim3(THREADS), 0, stream>>>(x, T, P, NS, G);
  gemm2<<<dim3(M_TOT / 8), dim3(256), 0, stream>>>(P, w, out, NS);
}